// Round 1
// baseline (44.799 us; speedup 1.0000x reference)
//
#include <hip/hip_runtime.h>
#include <math.h>

// QuantumGenerator: 4-qubit, 2-layer StronglyEntanglingLayers circuit + Linear(4,4).
// Math: out_j(x) = Tr(A_j * rho(x)) + b_j where rho(x) = prod_w (I + cos(x_w) Z - sin(x_w) Y)/2
// and A_j = sum_i W[j,i] * U^dag D_i U  (U = fixed layer unitary from q_weights).
// Precompute kernel builds the 81x4 Pauli-coefficient tensor D (bias folded into p=0 term);
// main kernel evaluates the 3^4 trig-tensor contraction per element.

__global__ __launch_bounds__(256) void qg_precompute(
    const float* __restrict__ qw,   // [2][4][3] (phi, theta, omega)
    const float* __restrict__ Wm,   // [4][4]
    const float* __restrict__ bv,   // [4]
    float* __restrict__ Dcoef)      // [81][4] output coefficients
{
  __shared__ float2 U[16][16];      // U[k][col]: column col evolved under layers
  __shared__ float  wj[4][16];      // wj[j][k] = sum_i W[j,i] * (1-2*bit_i(k))
  __shared__ float2 A[4][16][16];   // A[j][s][t]
  const int tid = threadIdx.x;

  // ---- Phase 1: build U columns (16 threads, one column each) ----
  if (tid < 16) {
    const int col = tid;
    #pragma unroll
    for (int k = 0; k < 16; ++k) U[k][col] = make_float2(k == col ? 1.f : 0.f, 0.f);
    for (int l = 0; l < 2; ++l) {
      for (int w = 0; w < 4; ++w) {
        const float phi = qw[(l*4 + w)*3 + 0];
        const float th  = qw[(l*4 + w)*3 + 1];
        const float om  = qw[(l*4 + w)*3 + 2];
        float st, ct, sa, ca, sd, cd;
        sincosf(0.5f*th,        &st, &ct);
        sincosf(0.5f*(phi+om),  &sa, &ca);
        sincosf(0.5f*(phi-om),  &sd, &cd);
        // Rot = [[e1*ct, -e2*st],[e3*st, e4*ct]], e1=(ca,-sa), e2=(cd,sd), e3=conj(e2), e4=conj(e1)
        const float2 m00 = make_float2( ca*ct, -sa*ct);
        const float2 m01 = make_float2(-cd*st, -sd*st);
        const float2 m10 = make_float2( cd*st, -sd*st);
        const float2 m11 = make_float2( ca*ct,  sa*ct);
        const int mask = 1 << (3 - w);
        #pragma unroll
        for (int k = 0; k < 16; ++k) if (!(k & mask)) {
          const float2 v0 = U[k][col], v1 = U[k | mask][col];
          const float2 n0 = make_float2(
              m00.x*v0.x - m00.y*v0.y + m01.x*v1.x - m01.y*v1.y,
              m00.x*v0.y + m00.y*v0.x + m01.x*v1.y + m01.y*v1.x);
          const float2 n1 = make_float2(
              m10.x*v0.x - m10.y*v0.y + m11.x*v1.x - m11.y*v1.y,
              m10.x*v0.y + m10.y*v0.x + m11.x*v1.y + m11.y*v1.x);
          U[k][col] = n0; U[k | mask][col] = n1;
        }
      }
      const int r = (l % 3) + 1;  // layer 0: r=1, layer 1: r=2
      for (int w = 0; w < 4; ++w) {
        const int t  = (w + r) & 3;
        const int cm = 1 << (3 - w), tm = 1 << (3 - t);
        #pragma unroll
        for (int k = 0; k < 16; ++k) if ((k & cm) && !(k & tm)) {
          const float2 tmp = U[k][col];
          U[k][col] = U[k | tm][col];
          U[k | tm][col] = tmp;
        }
      }
    }
  }
  // ---- Phase 2: wj table ----
  if (tid < 64) {
    const int j = tid >> 4, k = tid & 15;
    float s = 0.f;
    #pragma unroll
    for (int i = 0; i < 4; ++i)
      s += Wm[j*4 + i] * (((k >> (3 - i)) & 1) ? -1.f : 1.f);
    wj[j][k] = s;
  }
  __syncthreads();

  // ---- Phase 3a: A[j][s][t] = sum_k conj(U[k][s]) wj[j][k] U[k][t] ----
  {
    const int s = tid >> 4, t = tid & 15;
    float ar[4] = {0,0,0,0}, ai[4] = {0,0,0,0};
    #pragma unroll
    for (int k = 0; k < 16; ++k) {
      const float2 us = U[k][s], ut = U[k][t];
      const float pr = us.x*ut.x + us.y*ut.y;   // Re(conj(us)*ut)
      const float pi = us.x*ut.y - us.y*ut.x;   // Im(conj(us)*ut)
      #pragma unroll
      for (int j = 0; j < 4; ++j) { ar[j] += wj[j][k]*pr; ai[j] += wj[j][k]*pi; }
    }
    #pragma unroll
    for (int j = 0; j < 4; ++j) A[j][s][t] = make_float2(ar[j], ai[j]);
  }
  __syncthreads();

  // ---- Phase 3b: D_j[p] = (1/16) Tr(A_j * sigma_p), sigma in {I,Z,Y}^4 ----
  for (int item = tid; item < 324; item += 256) {
    const int j = item / 81, p = item % 81;
    const int p1 = p / 27, p2 = (p / 9) % 3, p3 = (p / 3) % 3, p4 = p % 3;
    int ym = 0, ny = 0;
    if (p1 == 2) { ym |= 8; ++ny; }
    if (p2 == 2) { ym |= 4; ++ny; }
    if (p3 == 2) { ym |= 2; ++ny; }
    if (p4 == 2) { ym |= 1; ++ny; }
    float sum = 0.f;
    for (int t = 0; t < 16; ++t) {
      const int t0 = (t>>3)&1, t1 = (t>>2)&1, t2 = (t>>1)&1, t3 = t&1;
      float sgn = 1.f;
      if      (p1 == 1) sgn *= t0 ? -1.f : 1.f;
      else if (p1 == 2) sgn *= t0 ?  1.f : -1.f;
      if      (p2 == 1) sgn *= t1 ? -1.f : 1.f;
      else if (p2 == 2) sgn *= t1 ?  1.f : -1.f;
      if      (p3 == 1) sgn *= t2 ? -1.f : 1.f;
      else if (p3 == 2) sgn *= t2 ?  1.f : -1.f;
      if      (p4 == 1) sgn *= t3 ? -1.f : 1.f;
      else if (p4 == 2) sgn *= t3 ?  1.f : -1.f;
      const float2 ae = A[j][t ^ ym][t];
      const int m = ny & 3;
      const float re = (m == 0) ? ae.x : (m == 1) ? -ae.y : (m == 2) ? -ae.x : ae.y;
      sum += sgn * re;
    }
    sum *= 0.0625f;
    if (p == 0) sum += bv[j];   // fold bias into the constant (all-I) term
    Dcoef[p*4 + j] = sum;
  }
}

template<int E>
__global__ __launch_bounds__(256) void qg_main(
    const float4* __restrict__ noise,   // [B] of float4 (x0..x3)
    const float4* __restrict__ Dcoef,   // [81] of float4 (j=0..3)
    float4* __restrict__ out,           // [B] of float4
    int B)
{
  __shared__ float4 Dl[81];
  for (int i = threadIdx.x; i < 81; i += 256) Dl[i] = Dcoef[i];
  __syncthreads();

  const int base = blockIdx.x * (256*E) + threadIdx.x;

  float g12[E][9], g34[E][9];
  #pragma unroll
  for (int e = 0; e < E; ++e) {
    const int idx = base + e*256;
    const float4 x = (idx < B) ? noise[idx] : make_float4(0.f,0.f,0.f,0.f);
    float s0,c0,s1,c1,s2,c2,s3,c3;
    __sincosf(x.x, &s0, &c0);
    __sincosf(x.y, &s1, &c1);
    __sincosf(x.z, &s2, &c2);
    __sincosf(x.w, &s3, &c3);
    g12[e][0] = 1.f;    g12[e][1] = c1;      g12[e][2] = -s1;
    g12[e][3] = c0;     g12[e][4] = c0*c1;   g12[e][5] = -c0*s1;
    g12[e][6] = -s0;    g12[e][7] = -s0*c1;  g12[e][8] = s0*s1;
    g34[e][0] = 1.f;    g34[e][1] = c3;      g34[e][2] = -s3;
    g34[e][3] = c2;     g34[e][4] = c2*c3;   g34[e][5] = -c2*s3;
    g34[e][6] = -s2;    g34[e][7] = -s2*c3;  g34[e][8] = s2*s3;
  }

  float acc0[E] = {}, acc1[E] = {}, acc2[E] = {}, acc3[E] = {};
  #pragma unroll
  for (int a = 0; a < 9; ++a) {
    float h0[E] = {}, h1[E] = {}, h2[E] = {}, h3[E] = {};
    #pragma unroll
    for (int bq = 0; bq < 9; ++bq) {
      const float4 d = Dl[a*9 + bq];   // uniform address -> LDS broadcast
      #pragma unroll
      for (int e = 0; e < E; ++e) {
        const float g = g34[e][bq];
        h0[e] = fmaf(d.x, g, h0[e]);
        h1[e] = fmaf(d.y, g, h1[e]);
        h2[e] = fmaf(d.z, g, h2[e]);
        h3[e] = fmaf(d.w, g, h3[e]);
      }
    }
    #pragma unroll
    for (int e = 0; e < E; ++e) {
      const float g = g12[e][a];
      acc0[e] = fmaf(g, h0[e], acc0[e]);
      acc1[e] = fmaf(g, h1[e], acc1[e]);
      acc2[e] = fmaf(g, h2[e], acc2[e]);
      acc3[e] = fmaf(g, h3[e], acc3[e]);
    }
  }

  #pragma unroll
  for (int e = 0; e < E; ++e) {
    const int idx = base + e*256;
    if (idx < B)
      out[idx] = make_float4(fabsf(acc0[e]) + 0.001f, acc1[e], acc2[e], acc3[e]);
  }
}

extern "C" void kernel_launch(void* const* d_in, const int* in_sizes, int n_in,
                              void* d_out, int out_size, void* d_ws, size_t ws_size,
                              hipStream_t stream) {
  const float* noise = (const float*)d_in[0];   // [B,4]
  const float* qw    = (const float*)d_in[1];   // [2,4,3]
  const float* Wm    = (const float*)d_in[2];   // [4,4]
  const float* bv    = (const float*)d_in[3];   // [4]
  float* Dcoef = (float*)d_ws;                  // 81*4 floats
  const int B = in_sizes[0] / 4;

  hipLaunchKernelGGL(qg_precompute, dim3(1), dim3(256), 0, stream, qw, Wm, bv, Dcoef);

  constexpr int E = 4;
  const int blocks = (B + 256*E - 1) / (256*E);
  hipLaunchKernelGGL(qg_main<E>, dim3(blocks), dim3(256), 0, stream,
                     (const float4*)noise, (const float4*)Dcoef, (float4*)d_out, B);
}

// Round 2
// 28.083 us; speedup vs baseline: 1.5952x; 1.5952x over previous
//
#include <hip/hip_runtime.h>
#include <math.h>

// QuantumGenerator: 4-qubit, 2-layer StronglyEntanglingLayers circuit + Linear(4,4).
// out_j(x) = sum_{p in {I,Z,Y}^4} D_j[p] * prod_w f_{p_w}(x_w),  f = (1, cos, -sin).
// qg_precompute builds the 81x4 coefficient table D (bias folded into the all-I term).
// qg_main evaluates the factored 3^4 contraction per element with all-scalar registers
// and wave-uniform (scalar-pipe) reads of D.

__global__ __launch_bounds__(256) void qg_precompute(
    const float* __restrict__ qw,   // [2][4][3] (phi, theta, omega)
    const float* __restrict__ Wm,   // [4][4]
    const float* __restrict__ bv,   // [4]
    float* __restrict__ Dcoef)      // [81][4]
{
  __shared__ float2 U[16][16];      // U[k][col]
  __shared__ float  wj[4][16];
  __shared__ float2 A[4][16][16];
  const int tid = threadIdx.x;

  // ---- Phase 1: build U columns in registers (16 threads, one column each) ----
  if (tid < 16) {
    const int col = tid;
    float ur[16], ui[16];
    #pragma unroll
    for (int k = 0; k < 16; ++k) { ur[k] = (k == col) ? 1.f : 0.f; ui[k] = 0.f; }
    #pragma unroll
    for (int l = 0; l < 2; ++l) {
      #pragma unroll
      for (int w = 0; w < 4; ++w) {
        const float phi = qw[(l*4 + w)*3 + 0];
        const float th  = qw[(l*4 + w)*3 + 1];
        const float om  = qw[(l*4 + w)*3 + 2];
        float st, ct, sa, ca, sd, cd;
        sincosf(0.5f*th,       &st, &ct);
        sincosf(0.5f*(phi+om), &sa, &ca);
        sincosf(0.5f*(phi-om), &sd, &cd);
        const float m00r =  ca*ct, m00i = -sa*ct;
        const float m01r = -cd*st, m01i = -sd*st;
        const float m10r =  cd*st, m10i = -sd*st;
        const float m11r =  ca*ct, m11i =  sa*ct;
        const int mask = 1 << (3 - w);
        #pragma unroll
        for (int k = 0; k < 16; ++k) if (!(k & mask)) {
          const int k1 = k | mask;
          const float v0r = ur[k],  v0i = ui[k];
          const float v1r = ur[k1], v1i = ui[k1];
          ur[k]  = m00r*v0r - m00i*v0i + m01r*v1r - m01i*v1i;
          ui[k]  = m00r*v0i + m00i*v0r + m01r*v1i + m01i*v1r;
          ur[k1] = m10r*v0r - m10i*v0i + m11r*v1r - m11i*v1i;
          ui[k1] = m10r*v0i + m10i*v0r + m11r*v1i + m11i*v1r;
        }
      }
      const int r = l + 1;  // StronglyEntanglingLayers default ranges for 2 layers
      #pragma unroll
      for (int w = 0; w < 4; ++w) {
        const int t  = (w + r) & 3;
        const int cm = 1 << (3 - w), tm = 1 << (3 - t);
        #pragma unroll
        for (int k = 0; k < 16; ++k) if ((k & cm) && !(k & tm)) {
          const int k1 = k | tm;
          const float tr = ur[k], ti = ui[k];
          ur[k] = ur[k1]; ui[k] = ui[k1];
          ur[k1] = tr;    ui[k1] = ti;
        }
      }
    }
    #pragma unroll
    for (int k = 0; k < 16; ++k) U[k][col] = make_float2(ur[k], ui[k]);
  }
  // ---- Phase 2: wj[j][k] = sum_i W[j,i]*(1-2*bit_i(k)) ----
  if (tid < 64) {
    const int j = tid >> 4, k = tid & 15;
    float s = 0.f;
    #pragma unroll
    for (int i = 0; i < 4; ++i)
      s += Wm[j*4 + i] * (((k >> (3 - i)) & 1) ? -1.f : 1.f);
    wj[j][k] = s;
  }
  __syncthreads();

  // ---- Phase 3a: A[j][s][t] = sum_k conj(U[k][s]) wj[j][k] U[k][t] ----
  {
    const int s = tid >> 4, t = tid & 15;
    float ar[4] = {0,0,0,0}, ai[4] = {0,0,0,0};
    #pragma unroll
    for (int k = 0; k < 16; ++k) {
      const float2 us = U[k][s], ut = U[k][t];
      const float pr = us.x*ut.x + us.y*ut.y;
      const float pi = us.x*ut.y - us.y*ut.x;
      #pragma unroll
      for (int j = 0; j < 4; ++j) { ar[j] += wj[j][k]*pr; ai[j] += wj[j][k]*pi; }
    }
    #pragma unroll
    for (int j = 0; j < 4; ++j) A[j][s][t] = make_float2(ar[j], ai[j]);
  }
  __syncthreads();

  // ---- Phase 3b: D_j[p] = (1/16) Tr(A_j sigma_p), sigma in {I,Z,Y}^4 ----
  for (int item = tid; item < 324; item += 256) {
    const int j = item / 81, p = item % 81;
    const int p1 = p / 27, p2 = (p / 9) % 3, p3 = (p / 3) % 3, p4 = p % 3;
    int ym = 0, ny = 0;
    if (p1 == 2) { ym |= 8; ++ny; }
    if (p2 == 2) { ym |= 4; ++ny; }
    if (p3 == 2) { ym |= 2; ++ny; }
    if (p4 == 2) { ym |= 1; ++ny; }
    float sum = 0.f;
    for (int t = 0; t < 16; ++t) {
      const int t0 = (t>>3)&1, t1 = (t>>2)&1, t2 = (t>>1)&1, t3 = t&1;
      float sgn = 1.f;
      if      (p1 == 1) sgn *= t0 ? -1.f : 1.f;
      else if (p1 == 2) sgn *= t0 ?  1.f : -1.f;
      if      (p2 == 1) sgn *= t1 ? -1.f : 1.f;
      else if (p2 == 2) sgn *= t1 ?  1.f : -1.f;
      if      (p3 == 1) sgn *= t2 ? -1.f : 1.f;
      else if (p3 == 2) sgn *= t2 ?  1.f : -1.f;
      if      (p4 == 1) sgn *= t3 ? -1.f : 1.f;
      else if (p4 == 2) sgn *= t3 ?  1.f : -1.f;
      const float2 ae = A[j][t ^ ym][t];
      const int m = ny & 3;
      const float re = (m == 0) ? ae.x : (m == 1) ? -ae.y : (m == 2) ? -ae.x : ae.y;
      sum += sgn * re;
    }
    sum *= 0.0625f;
    if (p == 0) sum += bv[j];
    Dcoef[p*4 + j] = sum;
  }
}

__global__ __launch_bounds__(256) void qg_main(
    const float4* __restrict__ noise,   // [B] float4 (x0..x3)
    const float*  __restrict__ D,       // [81][4], wave-uniform reads -> s_load
    float4* __restrict__ out,           // [B] float4
    int B)
{
  const int idx = blockIdx.x * 256 + threadIdx.x;
  if (idx >= B) return;

  const float4 x = noise[idx];
  float s0,c0,s1,c1,s2,c2,s3,c3;
  __sincosf(x.x, &s0, &c0);
  __sincosf(x.y, &s1, &c1);
  __sincosf(x.z, &s2, &c2);
  __sincosf(x.w, &s3, &c3);

  // f = (1, cos, -sin); g12[a] = f1[a/3]*f2[a%3]; g34[b] = f3[b/3]*f4[b%3]
  const float g34_1 = c3,     g34_2 = -s3,
              g34_3 = c2,     g34_4 = c2*c3, g34_5 = -c2*s3,
              g34_6 = -s2,    g34_7 = -s2*c3, g34_8 = s2*s3;
  const float g12_1 = c1,     g12_2 = -s1,
              g12_3 = c0,     g12_4 = c0*c1, g12_5 = -c0*s1,
              g12_6 = -s0,    g12_7 = -s0*c1, g12_8 = s0*s1;

  float h0, h1, h2, h3, acc0, acc1, acc2, acc3;

#define DA(a,b,j) D[((a)*9 + (b))*4 + (j)]
#define HT(a,b,g) \
  h0 = fmaf(DA(a,b,0), (g), h0); h1 = fmaf(DA(a,b,1), (g), h1); \
  h2 = fmaf(DA(a,b,2), (g), h2); h3 = fmaf(DA(a,b,3), (g), h3);
#define HB(a) \
  h0 = DA(a,0,0); h1 = DA(a,0,1); h2 = DA(a,0,2); h3 = DA(a,0,3); \
  HT(a,1,g34_1) HT(a,2,g34_2) HT(a,3,g34_3) HT(a,4,g34_4) \
  HT(a,5,g34_5) HT(a,6,g34_6) HT(a,7,g34_7) HT(a,8,g34_8)
#define ACC(a,g) \
  acc0 = fmaf((g), h0, acc0); acc1 = fmaf((g), h1, acc1); \
  acc2 = fmaf((g), h2, acc2); acc3 = fmaf((g), h3, acc3);

  HB(0) acc0 = h0; acc1 = h1; acc2 = h2; acc3 = h3;
  HB(1) ACC(1, g12_1)
  HB(2) ACC(2, g12_2)
  HB(3) ACC(3, g12_3)
  HB(4) ACC(4, g12_4)
  HB(5) ACC(5, g12_5)
  HB(6) ACC(6, g12_6)
  HB(7) ACC(7, g12_7)
  HB(8) ACC(8, g12_8)

#undef DA
#undef HT
#undef HB
#undef ACC

  out[idx] = make_float4(fabsf(acc0) + 0.001f, acc1, acc2, acc3);
}

extern "C" void kernel_launch(void* const* d_in, const int* in_sizes, int n_in,
                              void* d_out, int out_size, void* d_ws, size_t ws_size,
                              hipStream_t stream) {
  const float* noise = (const float*)d_in[0];   // [B,4]
  const float* qw    = (const float*)d_in[1];   // [2,4,3]
  const float* Wm    = (const float*)d_in[2];   // [4,4]
  const float* bv    = (const float*)d_in[3];   // [4]
  float* Dcoef = (float*)d_ws;                  // 81*4 floats
  const int B = in_sizes[0] / 4;

  hipLaunchKernelGGL(qg_precompute, dim3(1), dim3(256), 0, stream, qw, Wm, bv, Dcoef);

  const int blocks = (B + 255) / 256;
  hipLaunchKernelGGL(qg_main, dim3(blocks), dim3(256), 0, stream,
                     (const float4*)noise, (const float*)Dcoef, (float4*)d_out, B);
}